// Round 9
// baseline (113.173 us; speedup 1.0000x reference)
//
#include <hip/hip_runtime.h>

#define BATCH  65536
#define NIN    9
#define NHID   100
#define TSTEPS 25
#define CHUNK  5
#define EPS    3e-5f

typedef float v2f __attribute__((ext_vector_type(2)));

// ROUND-25: t-halving to break the register-occupancy wall. Evidence:
// OccupancyPercent ~25% = 2 waves/SIMD (grid supplies 4); LDS/block-size
// don't limit -> per-thread registers do (44 arch + fat AGPR blob for
// a0/a1[25]+temps). At 2 waves/SIMD, VALUBusy 70% == each wave issuing
// ~35% of cycles: latency-bound with too few waves. Fix: process t in two
// windows (0-14, 15-24). Accumulators shrink 50 -> 30/20 live; the cheap
// chain (4 ops/step) is replayed once (+~1.9K instr). Peak live ~57 regs
// -> 4 waves/SIMD reachable. Margin+__any only in pass 0; badmask reused
// in pass 1. Numerics bit-identical to R17: same chain fmaf sequence,
// same per-address accumulate order (main-j then patch-j, j ascending,
// per window), same butterfly + f64 mem2; chunk-buffer parity continues
// across halves (kg = 0..4) so the double-buffer protocol is unchanged.
__global__ __launch_bounds__(256, 4) void snn_kernel(
    const float* __restrict__ x,  const float* __restrict__ W1,
    const float* __restrict__ b1, const float* __restrict__ W2,
    const float* __restrict__ b2, float* __restrict__ out)
{
    __shared__ float sx[64 * NIN];              // 2.25 KB staged x rows
    __shared__ v2f   sacc[2][4][CHUNK][64];     // 20.5 KB double-buffered reduce

    const int tid  = threadIdx.x;
    const int lane = tid & 63;
    const int wq   = __builtin_amdgcn_readfirstlane(tid >> 6);
    const int b0   = blockIdx.x * 64;

    for (int i = tid; i < 64 * NIN; i += 256) sx[i] = x[(size_t)b0 * NIN + i];
    __syncthreads();

    // per-lane x row, f32 (exact input values)
    float xv[NIN];
#pragma unroll
    for (int i = 0; i < NIN; ++i) xv[i] = sx[lane * NIN + i];

    const int h0 = wq * 25;
    unsigned int badmask = 0;                  // wave-uniform fallback bits

    double m20 = 0.0, m21 = 0.0;               // wave0's mem2 chain state
    const double bb0 = (double)b2[0], bb1 = (double)b2[1];

    // ================= half 0: t in [0,15)  (30 live accs) =================
    {
        float a0[15], a1[15];
#pragma unroll
        for (int t = 0; t < 15; ++t) { a0[t] = 0.f; a1[t] = 0.f; }

#pragma unroll 1
        for (int j = 0; j < 25; ++j) {
            const int h = h0 + j;              // wave-uniform -> s_load weights
            float c32 = 0.f;
#pragma unroll
            for (int i = 0; i < NIN; ++i) c32 = fmaf(W1[h*NIN+i], xv[i], c32);
            c32 += b1[h];
            const float k  = c32 - 0.05f;      // u-chain: u = m-1
            const float k1 = c32 - 1.05f;
            const float w0 = W2[h], w1 = W2[NHID + h];

            float u = -1.0f, ming = 1e30f;
            bool  s = false;                   // spike(t-1) == reset(t)
#pragma unroll
            for (int t = 0; t < TSTEPS; ++t) {
                u = fmaf(0.95f, u, s ? k1 : k);
                s = (u > 0.0f);
                ming = fminf(ming, fabsf(u));  // margin (full chain, pass 0)
                if (t < 15) {                  // compile-time window
                    const float d = s ? 1.f : 0.f;
                    a0[t] = fmaf(d, w0, a0[t]);
                    a1[t] = fmaf(d, w1, a1[t]);
                }
            }
            if (__any(ming < EPS)) {           // rare wave-uniform fallback
                badmask |= (1u << j);
                double c64 = 0.0;
#pragma unroll
                for (int i = 0; i < NIN; ++i)
                    c64 += (double)W1[h*NIN+i] * (double)xv[i];
                c64 += (double)b1[h];
                const double c1 = c64 - 1.0;
                float  ur = -1.0f; bool sr = false;  // f32 replay == main
                double md = 0.0;   bool sd = false;  // exact f64 chain
#pragma unroll
                for (int t = 0; t < TSTEPS; ++t) {
                    ur = fmaf(0.95f, ur, sr ? k1 : k);
                    sr = (ur > 0.0f);
                    md = 0.95 * md + (sd ? c1 : c64);
                    sd = (md > 1.0);
                    if (t < 15 && sr != sd) {        // patch this window
                        const float sg = sd ? 1.f : -1.f;
                        a0[t] = fmaf(sg, w0, a0[t]);
                        a1[t] = fmaf(sg, w1, a1[t]);
                    }
                }
            }
        }
        // chunks kg = 0,1,2 (parity continues into half 1)
#pragma unroll
        for (int kc = 0; kc < 3; ++kc) {
#pragma unroll
            for (int u2 = 0; u2 < CHUNK; ++u2)
                sacc[kc & 1][wq][u2][lane] =
                    (v2f){a0[kc*CHUNK + u2], a1[kc*CHUNK + u2]};
            __syncthreads();
            if (wq == 0) {
#pragma unroll
                for (int u2 = 0; u2 < CHUNK; ++u2) {
                    const int t = kc*CHUNK + u2;
                    v2f q0 = sacc[kc & 1][0][u2][lane];
                    v2f q1 = sacc[kc & 1][1][u2][lane];
                    v2f q2 = sacc[kc & 1][2][u2][lane];
                    v2f q3 = sacc[kc & 1][3][u2][lane];
                    v2f sum = (q0 + q1) + (q2 + q3);   // butterfly bracketing
                    double r0 = (m20 > 1.0) ? 1.0 : 0.0;
                    double r1 = (m21 > 1.0) ? 1.0 : 0.0;
                    m20 = 0.95*m20 + ((double)sum[0] + bb0) - r0;
                    m21 = 0.95*m21 + ((double)sum[1] + bb1) - r1;
                    *(float2*)(out + ((size_t)t*BATCH + b0 + lane)*2) =
                        make_float2((float)m20, (float)m21);
                }
            }
        }
    }

    // ================= half 1: t in [15,25)  (20 live accs) ================
    {
        float a0[10], a1[10];
#pragma unroll
        for (int t = 0; t < 10; ++t) { a0[t] = 0.f; a1[t] = 0.f; }

#pragma unroll 1
        for (int j = 0; j < 25; ++j) {
            const int h = h0 + j;
            float c32 = 0.f;
#pragma unroll
            for (int i = 0; i < NIN; ++i) c32 = fmaf(W1[h*NIN+i], xv[i], c32);
            c32 += b1[h];
            const float k  = c32 - 0.05f;
            const float k1 = c32 - 1.05f;
            const float w0 = W2[h], w1 = W2[NHID + h];

            float u = -1.0f;                   // replay: no margin tracking
            bool  s = false;
#pragma unroll
            for (int t = 0; t < TSTEPS; ++t) {
                u = fmaf(0.95f, u, s ? k1 : k);
                s = (u > 0.0f);
                if (t >= 15) {
                    const float d = s ? 1.f : 0.f;
                    a0[t-15] = fmaf(d, w0, a0[t-15]);
                    a1[t-15] = fmaf(d, w1, a1[t-15]);
                }
            }
            if ((badmask >> j) & 1u) {         // wave-uniform, from pass 0
                double c64 = 0.0;
#pragma unroll
                for (int i = 0; i < NIN; ++i)
                    c64 += (double)W1[h*NIN+i] * (double)xv[i];
                c64 += (double)b1[h];
                const double c1 = c64 - 1.0;
                float  ur = -1.0f; bool sr = false;
                double md = 0.0;   bool sd = false;
#pragma unroll
                for (int t = 0; t < TSTEPS; ++t) {
                    ur = fmaf(0.95f, ur, sr ? k1 : k);
                    sr = (ur > 0.0f);
                    md = 0.95 * md + (sd ? c1 : c64);
                    sd = (md > 1.0);
                    if (t >= 15 && sr != sd) {
                        const float sg = sd ? 1.f : -1.f;
                        a0[t-15] = fmaf(sg, w0, a0[t-15]);
                        a1[t-15] = fmaf(sg, w1, a1[t-15]);
                    }
                }
            }
        }
        // chunks kg = 3,4 (parity 1,0 — double-buffer protocol continues)
#pragma unroll
        for (int kc = 0; kc < 2; ++kc) {
            const int kg = 3 + kc;
#pragma unroll
            for (int u2 = 0; u2 < CHUNK; ++u2)
                sacc[kg & 1][wq][u2][lane] =
                    (v2f){a0[kc*CHUNK + u2], a1[kc*CHUNK + u2]};
            __syncthreads();
            if (wq == 0) {
#pragma unroll
                for (int u2 = 0; u2 < CHUNK; ++u2) {
                    const int t = 15 + kc*CHUNK + u2;
                    v2f q0 = sacc[kg & 1][0][u2][lane];
                    v2f q1 = sacc[kg & 1][1][u2][lane];
                    v2f q2 = sacc[kg & 1][2][u2][lane];
                    v2f q3 = sacc[kg & 1][3][u2][lane];
                    v2f sum = (q0 + q1) + (q2 + q3);
                    double r0 = (m20 > 1.0) ? 1.0 : 0.0;
                    double r1 = (m21 > 1.0) ? 1.0 : 0.0;
                    m20 = 0.95*m20 + ((double)sum[0] + bb0) - r0;
                    m21 = 0.95*m21 + ((double)sum[1] + bb1) - r1;
                    *(float2*)(out + ((size_t)t*BATCH + b0 + lane)*2) =
                        make_float2((float)m20, (float)m21);
                }
            }
        }
    }
}

extern "C" void kernel_launch(void* const* d_in, const int* in_sizes, int n_in,
                              void* d_out, int out_size, void* d_ws, size_t ws_size,
                              hipStream_t stream) {
    const float* x  = (const float*)d_in[0];
    const float* W1 = (const float*)d_in[1];
    const float* b1 = (const float*)d_in[2];
    const float* W2 = (const float*)d_in[3];
    const float* b2 = (const float*)d_in[4];
    float* out = (float*)d_out;

    dim3 grid(BATCH / 64), block(256);
    hipLaunchKernelGGL(snn_kernel, grid, block, 0, stream, x, W1, b1, W2, b2, out);
}